// Round 1
// baseline (203.827 us; speedup 1.0000x reference)
//
#include <hip/hip_runtime.h>
#include <math.h>

#define D_MODEL 1024
#define SEQ 2048
#define NBATCH 4

using bf16x8 = __attribute__((ext_vector_type(8))) short;
using f32x4  = __attribute__((ext_vector_type(4))) float;

__device__ __forceinline__ unsigned short f2bf(float f) {
  union { float f; unsigned int u; } v; v.f = f;
  return (unsigned short)((v.u + 0x7fffu + ((v.u >> 16) & 1u)) >> 16);
}

__device__ __forceinline__ void async_cp16(const void* g, void* l) {
  __builtin_amdgcn_global_load_lds(
      (const __attribute__((address_space(1))) void*)g,
      (__attribute__((address_space(3))) void*)l, 16, 0, 0);
}

// ---------- prep_x: x fp32 -> bf16; s = x@Wo + bo; t = tanh(s) ----------
__global__ __launch_bounds__(256) void prep_x_kernel(
    const float* __restrict__ x, const float* __restrict__ Wo,
    const float* __restrict__ bo, unsigned short* __restrict__ xb,
    float* __restrict__ tb) {
  const int m = blockIdx.x;
  const int tid = threadIdx.x;
  const float4 xv = ((const float4*)(x + (size_t)m * D_MODEL))[tid];
  const float4 wv = ((const float4*)Wo)[tid];
  ushort4 o;
  o.x = f2bf(xv.x); o.y = f2bf(xv.y); o.z = f2bf(xv.z); o.w = f2bf(xv.w);
  ((ushort4*)(xb + (size_t)m * D_MODEL))[tid] = o;
  float p = xv.x * wv.x + xv.y * wv.y + xv.z * wv.z + xv.w * wv.w;
  #pragma unroll
  for (int off = 32; off > 0; off >>= 1) p += __shfl_down(p, off, 64);
  __shared__ float red[4];
  if ((tid & 63) == 0) red[tid >> 6] = p;
  __syncthreads();
  if (tid == 0) {
    float s = red[0] + red[1] + red[2] + red[3] + bo[0];
    tb[m] = tanhf(s);
  }
}

// ---------- prep_w: transpose W (K x N) -> WT (N x K) in bf16 ----------
__global__ __launch_bounds__(256) void prep_w_kernel(
    const float* __restrict__ Wq, const float* __restrict__ Wk,
    unsigned short* __restrict__ WqT, unsigned short* __restrict__ WkT) {
  const float* W = blockIdx.z ? Wk : Wq;
  unsigned short* WT = blockIdx.z ? WkT : WqT;
  const int k0 = blockIdx.y * 32, n0 = blockIdx.x * 32;
  __shared__ unsigned short lds[32][36];
  const int tid = threadIdx.x;
  const int r = tid >> 3, c = (tid & 7) * 4;
  float4 v = *(const float4*)(&W[(size_t)(k0 + r) * D_MODEL + n0 + c]);
  lds[r][c + 0] = f2bf(v.x); lds[r][c + 1] = f2bf(v.y);
  lds[r][c + 2] = f2bf(v.z); lds[r][c + 3] = f2bf(v.w);
  __syncthreads();
  ushort4 o;
  o.x = lds[c + 0][r]; o.y = lds[c + 1][r];
  o.z = lds[c + 2][r]; o.w = lds[c + 3][r];
  *(ushort4*)(&WT[(size_t)(n0 + r) * D_MODEL + k0 + c]) = o;
}

// ---------- qkgen: C = xb @ W^T-format(Bt) + bias, bf16 out ----------
// m97 recipe: 128x128 tile, BK=32, 4 waves each 64x64 (4x4 MFMA 16x16x32)
__global__ __launch_bounds__(256) void qkgen_kernel(
    const unsigned short* __restrict__ xb,
    const unsigned short* __restrict__ WqT,
    const unsigned short* __restrict__ WkT,
    const float* __restrict__ bq, const float* __restrict__ bk,
    unsigned short* __restrict__ Qb, unsigned short* __restrict__ Kb) {
  const unsigned short* Bt = blockIdx.z ? WkT : WqT;
  const float* bias = blockIdx.z ? bk : bq;
  unsigned short* Cout = blockIdx.z ? Kb : Qb;
  const int m0 = blockIdx.x * 128;
  const int n0 = blockIdx.y * 128;
  __shared__ unsigned short As[128 * 32];
  __shared__ unsigned short Bs[128 * 32];
  const int tid = threadIdx.x;
  const int lane = tid & 63, w = tid >> 6;
  const int wm = w >> 1, wn = w & 1;
  const int l16 = lane & 15, quad = lane >> 4;

  f32x4 acc[4][4];
  #pragma unroll
  for (int i = 0; i < 4; i++)
    #pragma unroll
    for (int j = 0; j < 4; j++) acc[i][j] = f32x4{0.f, 0.f, 0.f, 0.f};

  const int srow = tid >> 2;          // 0..63
  const int sseg = (tid & 3) * 8;     // k-offset (elements) of 16B segment
  const unsigned short* gA = xb + (size_t)(m0 + srow) * D_MODEL + sseg;
  const unsigned short* gB = Bt + (size_t)(n0 + srow) * D_MODEL + sseg;
  unsigned short* lA = As + tid * 8;  // == wave base + lane*16B
  unsigned short* lB = Bs + tid * 8;

  for (int k0 = 0; k0 < D_MODEL; k0 += 32) {
    async_cp16(gA + k0, lA);
    async_cp16(gA + k0 + (size_t)64 * D_MODEL, lA + 2048);
    async_cp16(gB + k0, lB);
    async_cp16(gB + k0 + (size_t)64 * D_MODEL, lB + 2048);
    __syncthreads();
    bf16x8 af[4], bfr[4];
    #pragma unroll
    for (int mt = 0; mt < 4; mt++)
      af[mt] = *(const bf16x8*)(As + (wm * 64 + mt * 16 + l16) * 32 + quad * 8);
    #pragma unroll
    for (int nt = 0; nt < 4; nt++)
      bfr[nt] = *(const bf16x8*)(Bs + (wn * 64 + nt * 16 + l16) * 32 + quad * 8);
    #pragma unroll
    for (int mt = 0; mt < 4; mt++)
      #pragma unroll
      for (int nt = 0; nt < 4; nt++)
        acc[mt][nt] = __builtin_amdgcn_mfma_f32_16x16x32_bf16(
            af[mt], bfr[nt], acc[mt][nt], 0, 0, 0);
    __syncthreads();
  }

  float bv[4];
  #pragma unroll
  for (int nt = 0; nt < 4; nt++) bv[nt] = bias[n0 + wn * 64 + nt * 16 + l16];
  #pragma unroll
  for (int mt = 0; mt < 4; mt++) {
    #pragma unroll
    for (int r = 0; r < 4; r++) {
      const int row = m0 + wm * 64 + mt * 16 + quad * 4 + r;
      unsigned short* cp = Cout + (size_t)row * D_MODEL + n0 + wn * 64 + l16;
      #pragma unroll
      for (int nt = 0; nt < 4; nt++)
        cp[nt * 16] = f2bf(acc[mt][nt][r] + bv[nt]);
    }
  }
}

// ---------- qkt: out[b,i,j] = 2^-5 * Q_i . K_j + 5*tanh(s_j - s_i) ----------
__global__ __launch_bounds__(256) void qkt_kernel(
    const unsigned short* __restrict__ Qb,
    const unsigned short* __restrict__ Kb,
    const float* __restrict__ tb, float* __restrict__ out) {
  const int b = blockIdx.z;
  const int i0 = blockIdx.x * 128;
  const int j0 = blockIdx.y * 128;
  const unsigned short* A = Qb + (size_t)b * SEQ * D_MODEL;
  const unsigned short* Bt = Kb + (size_t)b * SEQ * D_MODEL;
  __shared__ unsigned short As[128 * 32];
  __shared__ unsigned short Bs[128 * 32];
  __shared__ float tsi[128], tsj[128];
  const int tid = threadIdx.x;
  if (tid < 128) tsi[tid] = tb[b * SEQ + i0 + tid];
  else           tsj[tid - 128] = tb[b * SEQ + j0 + tid - 128];
  const int lane = tid & 63, w = tid >> 6;
  const int wm = w >> 1, wn = w & 1;
  const int l16 = lane & 15, quad = lane >> 4;

  f32x4 acc[4][4];
  #pragma unroll
  for (int i = 0; i < 4; i++)
    #pragma unroll
    for (int j = 0; j < 4; j++) acc[i][j] = f32x4{0.f, 0.f, 0.f, 0.f};

  const int srow = tid >> 2;
  const int sseg = (tid & 3) * 8;
  const unsigned short* gA = A + (size_t)(i0 + srow) * D_MODEL + sseg;
  const unsigned short* gB = Bt + (size_t)(j0 + srow) * D_MODEL + sseg;
  unsigned short* lA = As + tid * 8;
  unsigned short* lB = Bs + tid * 8;

  for (int k0 = 0; k0 < D_MODEL; k0 += 32) {
    async_cp16(gA + k0, lA);
    async_cp16(gA + k0 + (size_t)64 * D_MODEL, lA + 2048);
    async_cp16(gB + k0, lB);
    async_cp16(gB + k0 + (size_t)64 * D_MODEL, lB + 2048);
    __syncthreads();
    bf16x8 af[4], bfr[4];
    #pragma unroll
    for (int mt = 0; mt < 4; mt++)
      af[mt] = *(const bf16x8*)(As + (wm * 64 + mt * 16 + l16) * 32 + quad * 8);
    #pragma unroll
    for (int nt = 0; nt < 4; nt++)
      bfr[nt] = *(const bf16x8*)(Bs + (wn * 64 + nt * 16 + l16) * 32 + quad * 8);
    #pragma unroll
    for (int mt = 0; mt < 4; mt++)
      #pragma unroll
      for (int nt = 0; nt < 4; nt++)
        acc[mt][nt] = __builtin_amdgcn_mfma_f32_16x16x32_bf16(
            af[mt], bfr[nt], acc[mt][nt], 0, 0, 0);
    __syncthreads();
  }

  float tj[4];
  #pragma unroll
  for (int nt = 0; nt < 4; nt++) tj[nt] = tsj[wn * 64 + nt * 16 + l16];
  #pragma unroll
  for (int mt = 0; mt < 4; mt++) {
    #pragma unroll
    for (int r = 0; r < 4; r++) {
      const int il = wm * 64 + mt * 16 + quad * 4 + r;
      const float ti = tsi[il];
      float* cp = out + ((size_t)(b * SEQ + i0 + il)) * SEQ + j0 + wn * 64 + l16;
      #pragma unroll
      for (int nt = 0; nt < 4; nt++) {
        // tanh(sj - si) = (tj - ti) / (1 - tj*ti)
        const float num = tj[nt] - ti;
        const float den = fmaf(-tj[nt], ti, 1.0f);
        const float obias = 5.0f * num * __builtin_amdgcn_rcpf(den);
        cp[nt * 16] = 0.03125f * acc[mt][nt][r] + obias;
      }
    }
  }
}

extern "C" void kernel_launch(void* const* d_in, const int* in_sizes, int n_in,
                              void* d_out, int out_size, void* d_ws, size_t ws_size,
                              hipStream_t stream) {
  const float* x  = (const float*)d_in[0];
  const float* Wq = (const float*)d_in[1];
  const float* bq = (const float*)d_in[2];
  const float* Wk = (const float*)d_in[3];
  const float* bk = (const float*)d_in[4];
  const float* Wo = (const float*)d_in[5];
  const float* bo = (const float*)d_in[6];
  float* out = (float*)d_out;

  char* ws = (char*)d_ws;
  unsigned short* xb  = (unsigned short*)(ws);                        // 16 MiB
  unsigned short* WqT = (unsigned short*)(ws + (16ull << 20));        // 2 MiB
  unsigned short* WkT = (unsigned short*)(ws + (18ull << 20));        // 2 MiB
  unsigned short* Qb  = (unsigned short*)(ws + (20ull << 20));        // 16 MiB
  unsigned short* Kb  = (unsigned short*)(ws + (36ull << 20));        // 16 MiB
  float*          tb  = (float*)(ws + (52ull << 20));                 // 32 KiB

  prep_x_kernel<<<8192, 256, 0, stream>>>(x, Wo, bo, xb, tb);
  prep_w_kernel<<<dim3(32, 32, 2), 256, 0, stream>>>(Wq, Wk, WqT, WkT);
  qkgen_kernel<<<dim3(64, 8, 2), 256, 0, stream>>>(xb, WqT, WkT, bq, bk, Qb, Kb);
  qkt_kernel<<<dim3(16, 16, 4), 256, 0, stream>>>(Qb, Kb, tb, out);
}